// Round 2
// baseline (493.038 us; speedup 1.0000x reference)
//
#include <hip/hip_runtime.h>
#include <math.h>

// MessagePassingUnitGatingWithRelnessLogits fused kernel, MI355X (gfx950).
// N=32768 rows; D=1024 (paired=2048); A=256; FD=64; F8=8.
// Round 2: 8 rows/block (grid 4096), 256 threads, LDS ~37KB -> 4 blocks/CU
// (16 waves/CU, occupancy ~46%). Aux gate moved from 48-shuffle VALU chain
// to MFMA (K=256, F8 padded to 16). Main GEMM via mfma_f32_16x16x32_bf16.

#define EPS_LN 1e-5f

typedef __attribute__((ext_vector_type(8))) short short8;   // 8 x bf16
typedef __attribute__((ext_vector_type(4))) float f32x4;    // MFMA accumulator

__device__ __forceinline__ unsigned short f2bf(float f) {
  unsigned int u = __float_as_uint(f);
  u += 0x7FFFu + ((u >> 16) & 1u);      // round-to-nearest-even
  return (unsigned short)(u >> 16);
}

__device__ __forceinline__ float sigmoidf_(float x) {
  return 1.0f / (1.0f + __expf(-x));
}

// reverse_sigmoid forward: clip to [0.001,0.999], then logit
__device__ __forceinline__ float rsigf(float x) {
  float y = fminf(fmaxf(x, 0.001f), 0.999f);
  return logf(y) - log1pf(-y);
}

__device__ __forceinline__ ushort4 norm_pack(float4 x, float4 g, float4 b,
                                             float mu, float rstd) {
  ushort4 o;
  o.x = f2bf(fmaxf((x.x - mu) * rstd * g.x + b.x, 0.f));
  o.y = f2bf(fmaxf((x.y - mu) * rstd * g.y + b.y, 0.f));
  o.z = f2bf(fmaxf((x.z - mu) * rstd * g.z + b.z, 0.f));
  o.w = f2bf(fmaxf((x.w - mu) * rstd * g.w + b.w, 0.f));
  return o;
}

// ---------------------------------------------------------------------------
// Prep: W [2048][64] fp32 -> bf16 B-fragments in MFMA operand order (blocks
// 0..255), plus W_aux [256][8] -> padded 16-col B-fragments (blocks 256..263).
// frag[((ntile*64 + kb)*64 + lane)*8 + j] = bf16(W[k][f]),
//   f = ntile*16 + (lane&15), k = kb*32 + (lane>>4)*8 + j.
// ---------------------------------------------------------------------------
__global__ void prep_wfrag(const float* __restrict__ W,
                           const float* __restrict__ W_aux,
                           unsigned short* __restrict__ wfrag) {
  const int lane = threadIdx.x;
  const int b = blockIdx.x;
  unsigned short tmp[8];
  if (b < 256) {
    const int ntile = b >> 6;
    const int kb = b & 63;
    const int f = (ntile << 4) + (lane & 15);
    const int kbase = (kb << 5) + ((lane >> 4) << 3);
#pragma unroll
    for (int j = 0; j < 8; ++j) tmp[j] = f2bf(W[(size_t)(kbase + j) * 64 + f]);
    ushort4* dst = reinterpret_cast<ushort4*>(wfrag + (((size_t)b * 64 + lane) << 3));
    dst[0] = make_ushort4(tmp[0], tmp[1], tmp[2], tmp[3]);
    dst[1] = make_ushort4(tmp[4], tmp[5], tmp[6], tmp[7]);
  } else {
    const int kb = b - 256;                 // 0..7  (K=256)
    const int f = lane & 15;                // only f<8 real
    const int kbase = (kb << 5) + ((lane >> 4) << 3);
#pragma unroll
    for (int j = 0; j < 8; ++j)
      tmp[j] = (f < 8) ? f2bf(W_aux[(size_t)(kbase + j) * 8 + f]) : (unsigned short)0;
    ushort4* dst = reinterpret_cast<ushort4*>(
        wfrag + 131072 + (((size_t)kb * 64 + lane) << 3));
    dst[0] = make_ushort4(tmp[0], tmp[1], tmp[2], tmp[3]);
    dst[1] = make_ushort4(tmp[4], tmp[5], tmp[6], tmp[7]);
  }
}

// ---------------------------------------------------------------------------
// Main fused kernel. Block = 8 rows, 256 threads (4 waves).
// ---------------------------------------------------------------------------
__global__ void __launch_bounds__(256, 4) fused_main(
    const float* __restrict__ unary, const float* __restrict__ pair,
    const float* __restrict__ aux, const float* __restrict__ auxw,
    const float* __restrict__ ln_g, const float* __restrict__ ln_b,
    const float* __restrict__ b_lin,
    const float* __restrict__ ln_ag, const float* __restrict__ ln_ab,
    const float* __restrict__ b_aux,
    const float* __restrict__ gw, const float* __restrict__ agw,
    const unsigned short* __restrict__ wfrag,
    float* __restrict__ out, float* __restrict__ out_g) {
  // act: 8 rows x 2048 bf16, XOR-swizzled in 16B chunks (row stride 4096B
  // aliases to one bank otherwise). aux_act: 8 rows x 256 bf16, same swizzle.
  __shared__ unsigned short act_lds[8 * 2048];   // 32 KB
  __shared__ unsigned short aux_lds[8 * 256];    // 4 KB
  __shared__ float gate_part[4 * 8];             // [ntile][row]
  __shared__ float auxg_lds[8];

  const int tid = threadIdx.x;
  const int w = tid >> 6;     // wave 0..3
  const int lane = tid & 63;
  const int base = blockIdx.x << 3;

  // ------------------- phase 1: LN + relu -> LDS (bf16) --------------------
#pragma unroll
  for (int i = 0; i < 2; ++i) {
    const int rl = (w << 1) + i;         // local row 0..7
    const int row = base + rl;

    const float4* u4 = reinterpret_cast<const float4*>(unary + (size_t)row * 1024);
    const float4* p4 = reinterpret_cast<const float4*>(pair + (size_t)row * 1024);
    float4 uv[4], pv[4];
#pragma unroll
    for (int j = 0; j < 4; ++j) {
      uv[j] = u4[lane + 64 * j];
      pv[j] = p4[lane + 64 * j];
    }
    const float4 av = reinterpret_cast<const float4*>(aux + (size_t)row * 256)[lane];

    float s = 0.f, sq = 0.f;
#pragma unroll
    for (int j = 0; j < 4; ++j) {
      uv[j].x = fmaxf(uv[j].x, 0.f); uv[j].y = fmaxf(uv[j].y, 0.f);
      uv[j].z = fmaxf(uv[j].z, 0.f); uv[j].w = fmaxf(uv[j].w, 0.f);
      pv[j].x = fmaxf(pv[j].x, 0.f); pv[j].y = fmaxf(pv[j].y, 0.f);
      pv[j].z = fmaxf(pv[j].z, 0.f); pv[j].w = fmaxf(pv[j].w, 0.f);
      s += uv[j].x + uv[j].y + uv[j].z + uv[j].w;
      s += pv[j].x + pv[j].y + pv[j].z + pv[j].w;
      sq += uv[j].x * uv[j].x + uv[j].y * uv[j].y + uv[j].z * uv[j].z + uv[j].w * uv[j].w;
      sq += pv[j].x * pv[j].x + pv[j].y * pv[j].y + pv[j].z * pv[j].z + pv[j].w * pv[j].w;
    }
    float as = av.x + av.y + av.z + av.w;
    float asq = av.x * av.x + av.y * av.y + av.z * av.z + av.w * av.w;

    // one interleaved butterfly for all four reductions (6 stages)
#pragma unroll
    for (int d = 32; d; d >>= 1) {
      s += __shfl_xor(s, d);
      sq += __shfl_xor(sq, d);
      as += __shfl_xor(as, d);
      asq += __shfl_xor(asq, d);
    }
    const float mu = s * (1.f / 2048.f);
    const float rstd = rsqrtf(sq * (1.f / 2048.f) - mu * mu + EPS_LN);
    const float amu = as * (1.f / 256.f);
    const float arstd = rsqrtf(asq * (1.f / 256.f) - amu * amu + EPS_LN);

    const float4* g4 = reinterpret_cast<const float4*>(ln_g);
    const float4* bb4 = reinterpret_cast<const float4*>(ln_b);
#pragma unroll
    for (int j = 0; j < 4; ++j) {
      const int idx = lane + 64 * j;            // float4 index in half-row
      const int off = (lane & 1) << 2;          // ushort offset inside chunk
      // unary half: chunk c = idx>>1
      ushort4 o = norm_pack(uv[j], g4[idx], bb4[idx], mu, rstd);
      int addr = (rl << 11) + ((((idx >> 1)) ^ rl) << 3) + off;
      *reinterpret_cast<ushort4*>(&act_lds[addr]) = o;
      // pair half: chunk c = 128 + idx>>1
      ushort4 o2 = norm_pack(pv[j], g4[256 + idx], bb4[256 + idx], mu, rstd);
      int addr2 = (rl << 11) + (((128 + (idx >> 1)) ^ rl) << 3) + off;
      *reinterpret_cast<ushort4*>(&act_lds[addr2]) = o2;
    }
    // aux act: relu(LN(aux)) -> bf16, lane covers k = 4*lane..4*lane+3
    {
      const float4 ag = reinterpret_cast<const float4*>(ln_ag)[lane];
      const float4 ab = reinterpret_cast<const float4*>(ln_ab)[lane];
      ushort4 ao = norm_pack(av, ag, ab, amu, arstd);
      int addr = (rl << 8) + ((((lane >> 1)) ^ rl) << 3) + ((lane & 1) << 2);
      *reinterpret_cast<ushort4*>(&aux_lds[addr]) = ao;
    }
  }

  __syncthreads();

  // ------------------- phase 2: MFMA GEMMs ---------------------------------
  // Main: wave w owns f-tile w (f = 16w..16w+15). M=16 padded (rows clamped
  // to 0..7; rows 8..15 are duplicates, discarded).
  f32x4 acc = {0.f, 0.f, 0.f, 0.f};
  const int arow = lane & 7;    // clamped A row
  const int quad = lane >> 4;
  const unsigned short* wbase = wfrag + (((size_t)(w << 6)) << 9);
#pragma unroll 8
  for (int kb = 0; kb < 64; ++kb) {
    const short8 afrag = *reinterpret_cast<const short8*>(
        &act_lds[(arow << 11) + ((((kb << 2) + quad) ^ arow) << 3)]);
    const short8 bfrag = *reinterpret_cast<const short8*>(
        wbase + ((size_t)kb << 9) + (lane << 3));
    acc = __builtin_amdgcn_mfma_f32_16x16x32_bf16(afrag, bfrag, acc, 0, 0, 0);
  }
  // Aux GEMM on wave 0 only: K=256 -> 8 MFMAs.
  f32x4 aacc = {0.f, 0.f, 0.f, 0.f};
  if (w == 0) {
    const unsigned short* abase = wfrag + 131072;
#pragma unroll
    for (int kb = 0; kb < 8; ++kb) {
      const short8 afrag = *reinterpret_cast<const short8*>(
          &aux_lds[(arow << 8) + ((((kb << 2) + quad) ^ arow) << 3)]);
      const short8 bfrag = *reinterpret_cast<const short8*>(
          abase + ((size_t)kb << 9) + (lane << 3));
      aacc = __builtin_amdgcn_mfma_f32_16x16x32_bf16(afrag, bfrag, aacc, 0, 0, 0);
    }
  }

  // ------------------- epilogue: gate reductions ---------------------------
  // D layout: col(f-in-tile) = lane&15, row = quad*4 + reg.
  const int col = lane & 15;
  const float bl = b_lin[(w << 4) + col];
  float sred[4];
#pragma unroll
  for (int i = 0; i < 4; ++i) {
    float v = sigmoidf_(acc[i] + bl);
    v += __shfl_xor(v, 1);
    v += __shfl_xor(v, 2);
    v += __shfl_xor(v, 4);
    v += __shfl_xor(v, 8);   // sum over 16 f-cols (quad preserved)
    sred[i] = v;
  }
  if (col == 0 && quad < 2) {
#pragma unroll
    for (int i = 0; i < 4; ++i)
      gate_part[(w << 3) + (quad << 2) + i] = sred[i];
  }
  if (w == 0) {
    const float ba = b_aux[col & 7];
#pragma unroll
    for (int i = 0; i < 4; ++i) {
      float v = (col < 8) ? sigmoidf_(aacc[i] + ba) : 0.f;
      v += __shfl_xor(v, 1);
      v += __shfl_xor(v, 2);
      v += __shfl_xor(v, 4);
      v += __shfl_xor(v, 8);
      if (col == 0 && quad < 2) auxg_lds[(quad << 2) + i] = v * 0.125f;
    }
  }
  __syncthreads();

  // ------------------- epilogue: combine gates, scale pair -----------------
  const float gwt = gw[0];
  const float agwt = agw[0];
#pragma unroll
  for (int i = 0; i < 2; ++i) {
    const int rl = (w << 1) + i;
    const int row = base + rl;
    const float gate = (gate_part[rl] + gate_part[8 + rl] +
                        gate_part[16 + rl] + gate_part[24 + rl]) * (1.f / 64.f);
    const float auxg = auxg_lds[rl];
    const float logit = gwt * rsigf(gate) + agwt * rsigf(auxg);
    const float g = sigmoidf_(logit) * auxw[row];

    const float4* p4 = reinterpret_cast<const float4*>(pair + (size_t)row * 1024);
    float4* o4 = reinterpret_cast<float4*>(out + (size_t)row * 1024);
#pragma unroll
    for (int j = 0; j < 4; ++j) {
      float4 pv = p4[lane + 64 * j];
      pv.x *= g; pv.y *= g; pv.z *= g; pv.w *= g;
      o4[lane + 64 * j] = pv;
    }
    if (lane == 0) out_g[row] = g;
  }
}

extern "C" void kernel_launch(void* const* d_in, const int* in_sizes, int n_in,
                              void* d_out, int out_size, void* d_ws, size_t ws_size,
                              hipStream_t stream) {
  const float* unary = (const float*)d_in[0];
  const float* pair  = (const float*)d_in[1];
  const float* aux   = (const float*)d_in[2];
  const float* auxw  = (const float*)d_in[3];
  const float* ln_g  = (const float*)d_in[4];
  const float* ln_b  = (const float*)d_in[5];
  const float* W     = (const float*)d_in[6];
  const float* b     = (const float*)d_in[7];
  const float* ln_ag = (const float*)d_in[8];
  const float* ln_ab = (const float*)d_in[9];
  const float* W_aux = (const float*)d_in[10];
  const float* b_aux = (const float*)d_in[11];
  const float* gw    = (const float*)d_in[12];
  const float* agw   = (const float*)d_in[13];

  const int N = in_sizes[3];            // 32768
  unsigned short* wfrag = (unsigned short*)d_ws;   // 264 KB bf16 fragments
  float* out = (float*)d_out;
  float* out_g = out + (size_t)N * 1024;

  prep_wfrag<<<264, 64, 0, stream>>>(W, W_aux, wfrag);
  fused_main<<<N / 8, 256, 0, stream>>>(unary, pair, aux, auxw, ln_g, ln_b, b,
                                        ln_ag, ln_ab, b_aux, gw, agw,
                                        wfrag, out, out_g);
}